// Round 4
// baseline (1585.817 us; speedup 1.0000x reference)
//
#include <hip/hip_runtime.h>

#define NNODES 100000
#define NEDGES 3200000
#define NFEATS 128
#define HID 64
#define NGRAPHS 64
#define NPB 128                        // nodes per bucket (dst-range binning)
#define NBUCK ((NNODES + NPB - 1) / NPB)   // 782

// ---------- CSR build ----------

__global__ __launch_bounds__(256) void k_init(int* cnt_i, float* pooled, float* gcnt) {
    int i = blockIdx.x * 256 + threadIdx.x;
    if (i < NNODES) cnt_i[i] = 0;
    if (i < NGRAPHS * HID) pooled[i] = 0.f;
    if (i < NGRAPHS) gcnt[i] = 0.f;
}

__global__ __launch_bounds__(256) void k_count(const int* __restrict__ dst, int* __restrict__ cnt) {
    int e = blockIdx.x * 256 + threadIdx.x;
    if (e < NEDGES) atomicAdd(&cnt[dst[e]], 1);
}

// exclusive scan of cnt -> rowptr. 256 threads x 16 items = 4096/block.
__global__ __launch_bounds__(256) void k_scan1(const int* __restrict__ cnt, int* __restrict__ rowptr,
                                               int* __restrict__ bsums) {
    __shared__ int sh[256];
    int tid = threadIdx.x;
    int base = blockIdx.x * 4096 + tid * 16;
    int v[16];
    int s = 0;
#pragma unroll
    for (int p = 0; p < 16; p++) {
        int idx = base + p;
        int c = (idx < NNODES) ? cnt[idx] : 0;
        v[p] = s;
        s += c;
    }
    sh[tid] = s;
    __syncthreads();
    for (int off = 1; off < 256; off <<= 1) {
        int t = (tid >= off) ? sh[tid - off] : 0;
        __syncthreads();
        sh[tid] += t;
        __syncthreads();
    }
    int excl = tid ? sh[tid - 1] : 0;
#pragma unroll
    for (int p = 0; p < 16; p++) {
        int idx = base + p;
        if (idx < NNODES) rowptr[idx] = excl + v[p];
    }
    if (tid == 255) bsums[blockIdx.x] = sh[255];
}

__global__ void k_scan2(int* bsums, int nb) {
    int run = 0;
    for (int b = 0; b < nb; b++) { int t = bsums[b]; bsums[b] = run; run += t; }
}

__global__ __launch_bounds__(256) void k_scan3(const int* __restrict__ cnt, int* __restrict__ rowptr,
                                               int* __restrict__ cursor, float* __restrict__ dinv,
                                               const int* __restrict__ bsums, int* __restrict__ bcur) {
    int i = blockIdx.x * 256 + threadIdx.x;
    if (i >= NNODES) return;
    int r = rowptr[i] + bsums[i >> 12];
    rowptr[i] = r;
    cursor[i] = r;
    dinv[i] = rsqrtf((float)(cnt[i] + 1));   // +1 = self loop; always > 0
    if ((i & (NPB - 1)) == 0) bcur[i / NPB] = r;   // bucket append cursor = region start
}

// Pass A: append (s,d) into the dst's bucket region. Only NBUCK write heads
// -> active dirty lines stay L2-resident, full-line writebacks (no 8x ampl).
__global__ __launch_bounds__(256) void k_binA(const int* __restrict__ src, const int* __restrict__ dst,
                                              int* __restrict__ bcur, int2* __restrict__ ebin) {
    int e = blockIdx.x * 256 + threadIdx.x;
    if (e >= NEDGES) return;
    int s = src[e], d = dst[e];
    int p = atomicAdd(&bcur[d / NPB], 1);
    ebin[p] = make_int2(s, d);
}

// Pass B: one block per bucket; exact-position scatter confined to the
// bucket's contiguous ~32KB colw window (L2-resident).
__global__ __launch_bounds__(256) void k_binB(const int* __restrict__ rowptr, const float* __restrict__ dinv,
                                              const int2* __restrict__ ebin, int* __restrict__ cursor,
                                              float2* __restrict__ colw) {
    int b = blockIdx.x;
    int lo = rowptr[b * NPB];
    int hiNode = (b + 1) * NPB;
    int hi = (hiNode >= NNODES) ? NEDGES : rowptr[hiNode];
    for (int i = lo + threadIdx.x; i < hi; i += 256) {
        int2 r = ebin[i];
        float w = dinv[r.x] * dinv[r.y];
        int p = atomicAdd(&cursor[r.y], 1);
        colw[p] = make_float2(__int_as_float(r.x), w);
    }
}

// ---------- transform (GEMV per node, wave-uniform W -> s_load) ----------

#define CHK 32
#define CHKP 33   // +1 pad: conflict-free stride

// block = 128 nodes x 2 col-halves (256 threads). Thread owns 32 output cols
// of one node; acc in 32 VGPRs. x staged coalesced to LDS per 32-k chunk.
// Safe when in == agg: block reads exactly the rows it writes, and every
// global read precedes the final __syncthreads().
template <int K, bool RELU>
__global__ __launch_bounds__(256) void k_mm(const float* __restrict__ in, const float* __restrict__ W,
                                            const float* __restrict__ bias, const float* __restrict__ dinv,
                                            float* __restrict__ t_out, float* __restrict__ agg) {
    __shared__ float xs[128 * CHKP];
    const int tid = threadIdx.x;
    const int lane = tid & 63;
    const int wid = tid >> 6;
    // wave-uniform column half; pin to SGPR so W loads scalarize
    const int jhalf = __builtin_amdgcn_readfirstlane(wid & 1);
    const int nloc = (wid >> 1) * 64 + lane;   // 0..127 local node
    const int node0 = blockIdx.x * 128;
    const int node = node0 + nloc;

    float acc[32];
#pragma unroll
    for (int j = 0; j < 32; j++) acc[j] = 0.f;

    const int c4 = tid & 7;     // float4 slot in row (8 per 32-float chunk)
    const int r0 = tid >> 3;    // 0..31

    for (int ko = 0; ko < K; ko += CHK) {
        __syncthreads();
#pragma unroll
        for (int s = 0; s < 4; s++) {
            int r = r0 + s * 32;
            int gn = node0 + r;
            float4 v = make_float4(0.f, 0.f, 0.f, 0.f);
            if (gn < NNODES) v = *(const float4*)&in[(size_t)gn * K + ko + c4 * 4];
            if (RELU) {
                v.x = fmaxf(v.x, 0.f); v.y = fmaxf(v.y, 0.f);
                v.z = fmaxf(v.z, 0.f); v.w = fmaxf(v.w, 0.f);
            }
            float* dp = &xs[r * CHKP + c4 * 4];
            dp[0] = v.x; dp[1] = v.y; dp[2] = v.z; dp[3] = v.w;
        }
        __syncthreads();
        for (int kk = 0; kk < CHK; kk++) {
            float xk = xs[nloc * CHKP + kk];
            const float* Wr = &W[(size_t)(ko + kk) * 64 + jhalf * 32];
#pragma unroll
            for (int j = 0; j < 32; j++) acc[j] = fmaf(xk, Wr[j], acc[j]);
        }
    }

    if (node < NNODES) {
        float dv = dinv[node];
        float dv2 = dv * dv;
        float* tp = &t_out[(size_t)node * 64 + jhalf * 32];
        float* ap = &agg[(size_t)node * 64 + jhalf * 32];
#pragma unroll
        for (int j4 = 0; j4 < 8; j4++) {
            float4 tv = make_float4(acc[j4*4], acc[j4*4+1], acc[j4*4+2], acc[j4*4+3]);
            *(float4*)&tp[j4 * 4] = tv;
            float4 av;
            av.x = bias[jhalf*32 + j4*4 + 0] + tv.x * dv2;
            av.y = bias[jhalf*32 + j4*4 + 1] + tv.y * dv2;
            av.z = bias[jhalf*32 + j4*4 + 2] + tv.z * dv2;
            av.w = bias[jhalf*32 + j4*4 + 3] + tv.w * dv2;
            *(float4*)&ap[j4 * 4] = av;
        }
    }
}

// ---------- aggregation: 4 edges in flight, float4 gathers ----------

__global__ __launch_bounds__(256) void k_agg(const float* __restrict__ t, const int* __restrict__ rowptr,
                                             const int* __restrict__ cnt, const float2* __restrict__ colw,
                                             float* __restrict__ agg) {
    int w = (blockIdx.x * 256 + threadIdx.x) >> 6;   // node
    int lane = threadIdx.x & 63;
    if (w >= NNODES) return;
    int qg = lane >> 4;      // edge-slot group 0..3
    int ql = lane & 15;      // float4 slot within the 64-float row
    int start = rowptr[w];
    int n = cnt[w];
    float4 acc = make_float4(0.f, 0.f, 0.f, 0.f);
    for (int e = qg; e < n; e += 4) {
        float2 p = colw[start + e];
        float4 v = *(const float4*)&t[(size_t)__float_as_int(p.x) * 64 + ql * 4];
        acc.x = fmaf(p.y, v.x, acc.x);
        acc.y = fmaf(p.y, v.y, acc.y);
        acc.z = fmaf(p.y, v.z, acc.z);
        acc.w = fmaf(p.y, v.w, acc.w);
    }
    // reduce the 4 edge-slot groups (lanes l, l^16, l^32, l^48)
    acc.x += __shfl_xor(acc.x, 16); acc.y += __shfl_xor(acc.y, 16);
    acc.z += __shfl_xor(acc.z, 16); acc.w += __shfl_xor(acc.w, 16);
    acc.x += __shfl_xor(acc.x, 32); acc.y += __shfl_xor(acc.y, 32);
    acc.z += __shfl_xor(acc.z, 32); acc.w += __shfl_xor(acc.w, 32);
    if (qg == 0) {
        float4* ap = (float4*)&agg[(size_t)w * 64 + ql * 4];
        float4 o = *ap;
        o.x += acc.x; o.y += acc.y; o.z += acc.z; o.w += acc.w;
        *ap = o;
    }
}

// ---------- pooling + head ----------

// batch is SORTED: segmented reduction. One wave per POOL_CHUNK consecutive
// nodes (lane = feature); flush one atomicAdd per segment-within-chunk.
#define POOL_CHUNK 256
__global__ __launch_bounds__(256) void k_pool(const float* __restrict__ h, const int* __restrict__ batch,
                                              float* pooled, float* gcnt) {
    int w = (blockIdx.x * 256 + threadIdx.x) >> 6;
    int lane = threadIdx.x & 63;
    int start = w * POOL_CHUNK;
    if (start >= NNODES) return;
    int end = min(start + POOL_CHUNK, NNODES);
    int g = batch[start];
    float acc = 0.f;
    int cn = 0;
    for (int i = start; i < end; i++) {
        int gi = batch[i];
        if (gi != g) {
            atomicAdd(&pooled[g * 64 + lane], acc);
            if (lane == 0) atomicAdd(&gcnt[g], (float)cn);
            g = gi; acc = 0.f; cn = 0;
        }
        acc += fmaxf(h[i * 64 + lane], 0.f);   // relu of layer-3 output
        cn++;
    }
    atomicAdd(&pooled[g * 64 + lane], acc);
    if (lane == 0) atomicAdd(&gcnt[g], (float)cn);
}

__global__ __launch_bounds__(256) void k_final(const float* __restrict__ pooled, const float* __restrict__ gcnt,
                                               const float* __restrict__ Wl, const float* __restrict__ bl,
                                               float* __restrict__ out) {
    int g = (blockIdx.x * 256 + threadIdx.x) >> 6;
    int lane = threadIdx.x & 63;
    if (g >= NGRAPHS) return;
    float c = fmaxf(gcnt[g], 1.f);
    float v = pooled[g * 64 + lane] / c * Wl[lane];
#pragma unroll
    for (int off = 32; off; off >>= 1) v += __shfl_down(v, off);
    if (lane == 0) out[g] = v + bl[0];
}

// ---------- launch ----------

extern "C" void kernel_launch(void* const* d_in, const int* in_sizes, int n_in,
                              void* d_out, int out_size, void* d_ws, size_t ws_size,
                              hipStream_t stream) {
    const float* x  = (const float*)d_in[0];
    const int* ei   = (const int*)d_in[1];
    const int* batch = (const int*)d_in[2];
    const float* W1 = (const float*)d_in[3];
    const float* b1 = (const float*)d_in[4];
    const float* W2 = (const float*)d_in[5];
    const float* b2 = (const float*)d_in[6];
    const float* W3 = (const float*)d_in[7];
    const float* b3 = (const float*)d_in[8];
    const float* Wl = (const float*)d_in[9];
    const float* bl = (const float*)d_in[10];
    const int* src = ei;
    const int* dst = ei + NEDGES;

    char* ws = (char*)d_ws;
    size_t off = 0;
    auto alloc = [&](size_t bytes) { void* p = ws + off; off += (bytes + 255) & ~size_t(255); return p; };
    float*  A      = (float*)alloc((size_t)NNODES * 64 * 4);
    float*  B      = (float*)alloc((size_t)NNODES * 64 * 4);
    float2* colw   = (float2*)alloc((size_t)NEDGES * 8);
    float*  dinv   = (float*)alloc((size_t)NNODES * 4);
    int*    cnti   = (int*)alloc((size_t)NNODES * 4);
    int*    rowptr = (int*)alloc((size_t)NNODES * 4);
    int*    cursor = (int*)alloc((size_t)NNODES * 4);
    int*    bsums  = (int*)alloc(32 * 4);
    int*    bcur   = (int*)alloc(NBUCK * 4);
    float*  pooled = (float*)alloc(NGRAPHS * 64 * 4);
    float*  gcnt   = (float*)alloc(NGRAPHS * 4);
    float*  out    = (float*)d_out;
    int2*   ebin   = (int2*)A;   // pass-A staging aliases A (free until layer-1 k_mm)

    const int NB_N  = (NNODES + 255) / 256;
    const int NB_E  = (NEDGES + 255) / 256;
    const int NB_SC = (NNODES + 4095) / 4096;
    const int NB_MM = (NNODES + 127) / 128;
    const int NB_W  = ((size_t)NNODES * 64 + 255) / 256;
    const int NB_PL = ((NNODES + POOL_CHUNK - 1) / POOL_CHUNK + 3) / 4;

    k_init<<<NB_N, 256, 0, stream>>>(cnti, pooled, gcnt);
    k_count<<<NB_E, 256, 0, stream>>>(dst, cnti);
    k_scan1<<<NB_SC, 256, 0, stream>>>(cnti, rowptr, bsums);
    k_scan2<<<1, 1, 0, stream>>>(bsums, NB_SC);
    k_scan3<<<NB_N, 256, 0, stream>>>(cnti, rowptr, cursor, dinv, bsums, bcur);
    k_binA<<<NB_E, 256, 0, stream>>>(src, dst, bcur, ebin);
    k_binB<<<NBUCK, 256, 0, stream>>>(rowptr, dinv, ebin, cursor, colw);

    // layer 1: x[N,128] -> A (transform), B (agg init); then aggregate into B
    k_mm<128, false><<<NB_MM, 256, 0, stream>>>(x, W1, b1, dinv, A, B);
    k_agg<<<NB_W, 256, 0, stream>>>(A, rowptr, cnti, colw, B);
    // layer 2 (relu on read)
    k_mm<64, true><<<NB_MM, 256, 0, stream>>>(B, W2, b2, dinv, A, B);
    k_agg<<<NB_W, 256, 0, stream>>>(A, rowptr, cnti, colw, B);
    // layer 3
    k_mm<64, true><<<NB_MM, 256, 0, stream>>>(B, W3, b3, dinv, A, B);
    k_agg<<<NB_W, 256, 0, stream>>>(A, rowptr, cnti, colw, B);

    k_pool<<<NB_PL, 256, 0, stream>>>(B, batch, pooled, gcnt);
    k_final<<<(NGRAPHS * 64 + 255) / 256, 256, 0, stream>>>(pooled, gcnt, Wl, bl, out);
}